// Round 6
// baseline (299.582 us; speedup 1.0000x reference)
//
#include <hip/hip_runtime.h>
#include <stdint.h>

typedef unsigned long long u64;

#define NCAND   4096
#define M2      8192            // 2N
#define NWORDS  128             // M2/64
#define SCORE_T 0.5f
#define IOU_T   0.5f
#define JSPLIT  16              // j-range splits for the counting sort

// ---------------- workspace layout (bytes) ----------------
// hdr[0] = V (atomicMax in k_scatter; 0xAA poison is negative -> no init needed)
// hdr[1] = maxcoord f32 bits (atomicMax in k_build; poison negative -> safe)
#define OFF_HDR     0
#define OFF_KEYS    4096                       // u64[8192]
#define OFF_PART    (OFF_KEYS + 65536)         // int[JSPLIT][8192]
#define OFF_OAREA   (OFF_PART + JSPLIT*32768)  // float[8192]
#define OFF_SSCORE  (OFF_OAREA + 32768)        // float[8192] sorted original scores
#define OFF_SLABEL  (OFF_SSCORE + 32768)       // int[8192]   sorted labels
#define OFF_SB      (OFF_SLABEL + 32768)       // float4[8192] sorted boxes
#define OFF_OBOX    (OFF_SB + 131072)          // float4[8192] sorted offset boxes
#define OFF_MASK    (OFF_OBOX + 131072)        // u64 mask_T[128][8192]  (TRANSPOSED: word-major)
// total ≈ 9.4 MiB

__device__ __forceinline__ unsigned order_key(float f) {
    unsigned u = __float_as_uint(f);
    return (u & 0x80000000u) ? ~u : (u | 0x80000000u);  // ascending uint == ascending float
}

__device__ __forceinline__ float get_width(const int* widthp) {
    int wi = widthp[0];
    return (wi > 0 && wi < 1000000) ? (float)wi : __int_as_float(wi);
}

// Recompute the combined (flip-adjusted) candidate `idx` straight from inputs.
__device__ __forceinline__ void fetch_cand(int idx, const float* b1, const float* b2,
                                           const float* s1, const float* s2,
                                           const int* l1, const int* l2, float wf,
                                           float& x1, float& y1, float& x2, float& y2,
                                           float& sc, int& lb) {
#pragma clang fp contract(off)
    if (idx < NCAND) {
        x1 = b1[idx*4+0]; y1 = b1[idx*4+1]; x2 = b1[idx*4+2]; y2 = b1[idx*4+3];
        sc = s1[idx]; lb = l1[idx];
    } else {
        int m = idx - NCAND;
        float bx1 = b2[m*4+0], by1 = b2[m*4+1], bx2 = b2[m*4+2], by2 = b2[m*4+3];
        x1 = wf - bx2; y1 = by1; x2 = wf - bx1; y2 = by2;   // undo hflip, same IEEE ops as ref
        sc = s2[m]; lb = l2[m];
    }
}

// ---------------- kernel 1: keys + global max coordinate ----------------
extern "C" __global__ __launch_bounds__(512)
void k_build(const float* __restrict__ b1, const float* __restrict__ b2,
             const float* __restrict__ s1, const float* __restrict__ s2,
             const int* __restrict__ l1, const int* __restrict__ l2,
             const int* __restrict__ widthp, char* __restrict__ ws)
{
#pragma clang fp contract(off)
    const int e = blockIdx.x * 512 + threadIdx.x;
    const float wf = get_width(widthp);
    float x1, y1, x2, y2, sc; int lb;
    fetch_cand(e, b1, b2, s1, s2, l1, l2, wf, x1, y1, x2, y2, sc, lb);

    float lmax = fmaxf(fmaxf(x1, y1), fmaxf(x2, y2));   // coords >= 0 (clipped)
    for (int d = 32; d > 0; d >>= 1) lmax = fmaxf(lmax, __shfl_xor(lmax, d));
    if ((threadIdx.x & 63) == 0)
        atomicMax(((int*)(ws + OFF_HDR)) + 1, __float_as_int(lmax));  // poison < 0, safe

    bool valid = sc >= SCORE_T;
    float s = valid ? sc : -1.0f;
    u64 key = ((u64)order_key(-s) << 32) | (unsigned)e;  // low bits = idx -> stable argsort
    ((u64*)(ws + OFF_KEYS))[e] = key;
}

// ---------------- kernel 2: counting sort, partial ranks ----------------
extern "C" __global__ __launch_bounds__(256)
void k_count(char* __restrict__ ws)
{
    __shared__ u64 tile[M2 / JSPLIT];
    const u64* keys = (const u64*)(ws + OFF_KEYS);
    const int i = blockIdx.x * 256 + threadIdx.x;
    const u64 mykey = keys[i];
    const int j0 = blockIdx.y * (M2 / JSPLIT);
    for (int q = threadIdx.x; q < M2 / JSPLIT; q += 256) tile[q] = keys[j0 + q];
    __syncthreads();
    int cnt = 0;
#pragma unroll 8
    for (int q = 0; q < M2 / JSPLIT; ++q) cnt += (tile[q] < mykey) ? 1 : 0;
    ((int*)(ws + OFF_PART))[blockIdx.y * M2 + i] = cnt;
}

// ---------------- kernel 3: combine ranks + scatter + V ----------------
extern "C" __global__ __launch_bounds__(1024)
void k_scatter(const float* __restrict__ b1, const float* __restrict__ b2,
               const float* __restrict__ s1, const float* __restrict__ s2,
               const int* __restrict__ l1, const int* __restrict__ l2,
               const int* __restrict__ widthp, char* __restrict__ ws)
{
#pragma clang fp contract(off)
    const int i = blockIdx.x * 1024 + threadIdx.x;
    const int* part = (const int*)(ws + OFF_PART);
    int rank = 0;
#pragma unroll
    for (int sp = 0; sp < JSPLIT; ++sp) rank += part[sp * M2 + i];

    const float wf = get_width(widthp);
    const float maxc = __int_as_float(((const int*)(ws + OFF_HDR))[1]) + 1.0f; // jnp.max(boxes)+1.0
    float x1, y1, x2, y2, sc; int lb;
    fetch_cand(i, b1, b2, s1, s2, l1, l2, wf, x1, y1, x2, y2, sc, lb);

    float off = (float)lb * maxc;               // one product then 4 adds, like ref
    float ox1 = x1 + off, oy1 = y1 + off, ox2 = x2 + off, oy2 = y2 + off;
    float area = (ox2 - ox1) * (oy2 - oy1);     // area of OFFSET boxes, like ref

    ((float4*)(ws + OFF_SB))[rank]   = make_float4(x1, y1, x2, y2);
    ((float4*)(ws + OFF_OBOX))[rank] = make_float4(ox1, oy1, ox2, oy2);
    ((float*)(ws + OFF_OAREA))[rank]  = area;
    ((float*)(ws + OFF_SSCORE))[rank] = sc;
    ((int*)(ws + OFF_SLABEL))[rank]   = lb;

    // valid entries (score>=T) sort strictly before invalid (-1): V = max valid rank + 1
    bool valid = sc >= SCORE_T;
    u64 bal = __ballot(valid);
    int vmax = valid ? rank + 1 : INT32_MIN;
    for (int d = 32; d > 0; d >>= 1) vmax = max(vmax, __shfl_xor(vmax, d));
    if ((threadIdx.x & 63) == 0 && bal)
        atomicMax((int*)(ws + OFF_HDR), vmax);  // poison < 0, safe
}

// ---------------- kernel 4: lower-triangle conflict bitmask (TRANSPOSED store) ----------------
// grid (128, 32), 4 waves/block; wave g handles col word y = by*4+g vs row chunk x.
// Row boxes staged once per block in LDS (4x reuse, same-address broadcast reads).
extern "C" __global__ __launch_bounds__(256)
void k_mask(char* __restrict__ ws)
{
#pragma clang fp contract(off)
    __shared__ float4 sbox[64];
    __shared__ float  sarea[64];
    const int x = blockIdx.x;                   // row chunk
    const int V = ((const int*)(ws + OFF_HDR))[0];
    if (x * 64 >= V) return;                    // rows >= V never scanned

    const float4* obox  = (const float4*)(ws + OFF_OBOX);
    const float*  oarea = (const float*) (ws + OFF_OAREA);
    u64* maskT = (u64*)(ws + OFF_MASK);

    const int tid = threadIdx.x;
    if (tid < 64) { sbox[tid] = obox[x*64 + tid]; sarea[tid] = oarea[x*64 + tid]; }
    __syncthreads();

    const int g = tid >> 6, lane = tid & 63;
    const int y = blockIdx.y * 4 + g;           // col word
    if (y > x) return;                          // strictly-upper words never read (after barrier)

    const int col  = y * 64 + lane;
    const float4 cb = obox[col];
    const float  ca = oarea[col];

    for (int r = 0; r < 64; ++r) {
        int row = x * 64 + r;
        float4 rb = sbox[r];                    // LDS broadcast
        float  ra = sarea[r];
        float ltx = fmaxf(rb.x, cb.x);
        float lty = fmaxf(rb.y, cb.y);
        float rbx = fminf(rb.z, cb.z);
        float rby = fminf(rb.w, cb.w);
        float wx = fmaxf(rbx - ltx, 0.0f);      // jnp.clip(rb-lt, 0)
        float wy = fmaxf(rby - lty, 0.0f);
        float inter = wx * wy;
        float denom = ((ra + ca) - inter) + 1e-9f;  // ref association order
        float iou = inter / denom;
        u64 m = __ballot((col < row) && (iou > IOU_T));
        if (lane == 0) maskT[(size_t)y * M2 + row] = m;
    }
}

// ---------------- kernel 5: single-block LDS-chained exact NMS + fused output ----------------
// 16 waves; wave g owns words g, g+16, ... Chain hops via LDS. Mask rows are prefetched
// 16-deep into ping-pong register chunks (static unroll -> stays in VGPRs), so the global
// load latency (~900cy) is issued >= 16 hops ahead of use and fully hidden; the hop cost
// is poll-spin + AND + ballot fixpoint + publish (~300cy).
#define ISSUE_CHUNK(BUF, BASE)                                                  \
    _Pragma("unroll")                                                           \
    for (int i_ = 0; i_ < 16; ++i_) {                                           \
        int w_ = (BASE) + i_;                                                   \
        if (w_ < W) BUF[i_] = maskT[(size_t)w_ * M2 + R];                       \
    }

#define CONSUME_CHUNK(BUF, BASE)                                                \
    _Pragma("unroll")                                                           \
    for (int i_ = 0; i_ < 16; ++i_) {                                           \
        int w_ = (BASE) + i_;                                                   \
        if (w_ < W) {                                                           \
            int guard_ = 0;                                                     \
            while (__hip_atomic_load(&s_prog, __ATOMIC_ACQUIRE,                 \
                   __HIP_MEMORY_SCOPE_WORKGROUP) <= w_ &&                       \
                   ++guard_ < (1 << 20)) {}                                     \
            acc |= BUF[i_] & __hip_atomic_load(&keep_lds[w_], __ATOMIC_RELAXED, \
                   __HIP_MEMORY_SCOPE_WORKGROUP);                               \
        }                                                                       \
    }

extern "C" __global__ __launch_bounds__(1024)
void k_nms_out(char* __restrict__ ws, float* __restrict__ out)
{
    __shared__ u64 keep_lds[NWORDS];
    __shared__ int s_prog;
    const int tid = threadIdx.x;
    const int g = tid >> 6, lane = tid & 63;
    const int V = ((const int*)(ws + OFF_HDR))[0];
    const int nw = (V > 0) ? ((V + 63) >> 6) : 0;   // chain is the word prefix [0, nw)
    const u64* maskT = (const u64*)(ws + OFF_MASK);

    if (tid == 0) s_prog = 0;
    __syncthreads();

    for (int W = g; W < NWORDS; W += 16) {
        if (W >= nw) {                          // fully-invalid word: keep = 0, no chain
            if (lane == 0)
                __hip_atomic_store(&keep_lds[W], (u64)0, __ATOMIC_RELAXED, __HIP_MEMORY_SCOPE_WORKGROUP);
            continue;
        }
        const int R = W * 64 + lane;
        const u64 diag = maskT[(size_t)W * M2 + R];  // in-word lower-triangle conflicts
        u64 acc = 0;
        u64 A[16], B[16];
        ISSUE_CHUNK(A, 0)
        ISSUE_CHUNK(B, 16)
        CONSUME_CHUNK(A, 0)
        ISSUE_CHUNK(A, 32)
        CONSUME_CHUNK(B, 16)
        ISSUE_CHUNK(B, 48)
        CONSUME_CHUNK(A, 32)
        ISSUE_CHUNK(A, 64)
        CONSUME_CHUNK(B, 48)
        ISSUE_CHUNK(B, 80)
        CONSUME_CHUNK(A, 64)
        ISSUE_CHUNK(A, 96)
        CONSUME_CHUNK(B, 80)
        ISSUE_CHUNK(B, 112)
        CONSUME_CHUNK(A, 96)
        CONSUME_CHUNK(B, 112)

        const bool live = (R < V) && (acc == 0);     // not suppressed by earlier kept words
        u64 k = __ballot(live);
        for (int it = 0; it < 64; ++it) {            // unique triangular fixed point == greedy
            bool killed = (diag & k) != 0;
            u64 k2 = __ballot(live && !killed);
            if (k2 == k) break;
            k = k2;
        }
        if (lane == 0) {
            __hip_atomic_store(&keep_lds[W], k, __ATOMIC_RELAXED, __HIP_MEMORY_SCOPE_WORKGROUP);
            __hip_atomic_store(&s_prog, W + 1, __ATOMIC_RELEASE, __HIP_MEMORY_SCOPE_WORKGROUP);
        }
    }
    __syncthreads();

    // fused masked outputs: d_out (f32) = boxes[8192*4] | labels[8192] | scores[8192] | keeps[8192]
    for (int i = 0; i < M2 / 1024; ++i) {
        int p = tid + i * 1024;
        int kb = (int)((keep_lds[p >> 6] >> (p & 63)) & 1ull);
        float4 bx = ((const float4*)(ws + OFF_SB))[p];
        if (!kb) bx = make_float4(0.f, 0.f, 0.f, 0.f);
        ((float4*)out)[p] = bx;
        out[M2*4 + p] = kb ? (float)((const int*)(ws + OFF_SLABEL))[p] : -1.0f;
        out[M2*5 + p] = kb ? ((const float*)(ws + OFF_SSCORE))[p] : 0.0f;
        out[M2*6 + p] = kb ? 1.0f : 0.0f;
    }
}

extern "C" void kernel_launch(void* const* d_in, const int* in_sizes, int n_in,
                              void* d_out, int out_size, void* d_ws, size_t ws_size,
                              hipStream_t stream)
{
    const float* boxes1  = (const float*)d_in[0];
    const float* boxes2  = (const float*)d_in[1];
    const float* scores1 = (const float*)d_in[2];
    const float* scores2 = (const float*)d_in[3];
    const int*   labels1 = (const int*)d_in[4];
    const int*   labels2 = (const int*)d_in[5];
    const int*   widthp  = (const int*)d_in[6];
    char* ws = (char*)d_ws;

    hipLaunchKernelGGL(k_build, dim3(M2 / 512), dim3(512), 0, stream,
                       boxes1, boxes2, scores1, scores2, labels1, labels2, widthp, ws);
    hipLaunchKernelGGL(k_count, dim3(M2 / 256, JSPLIT), dim3(256), 0, stream, ws);
    hipLaunchKernelGGL(k_scatter, dim3(M2 / 1024), dim3(1024), 0, stream,
                       boxes1, boxes2, scores1, scores2, labels1, labels2, widthp, ws);
    hipLaunchKernelGGL(k_mask, dim3(NWORDS, 32), dim3(256), 0, stream, ws);
    hipLaunchKernelGGL(k_nms_out, dim3(1), dim3(1024), 0, stream, ws, (float*)d_out);
}

// Round 7
// 296.430 us; speedup vs baseline: 1.0106x; 1.0106x over previous
//
#include <hip/hip_runtime.h>
#include <stdint.h>

typedef unsigned long long u64;

#define NCAND   4096
#define M2      8192            // 2N
#define NWORDS  128             // M2/64
#define SCORE_T 0.5f
#define IOU_T   0.5f
#define JSPLIT  16              // j-range splits for the counting sort

// ---------------- workspace layout (bytes) ----------------
// hdr[0] = V (atomicMax in k_scatter; 0xAA poison is negative -> no init needed)
// hdr[1] = maxcoord f32 bits (atomicMax in k_build; poison negative -> safe)
#define OFF_HDR     0
#define OFF_KEYS    4096                       // u64[8192]
#define OFF_PART    (OFF_KEYS + 65536)         // int[JSPLIT][8192]
#define OFF_OAREA   (OFF_PART + JSPLIT*32768)  // float[8192]
#define OFF_SSCORE  (OFF_OAREA + 32768)        // float[8192] sorted original scores
#define OFF_SLABEL  (OFF_SSCORE + 32768)       // int[8192]   sorted labels
#define OFF_SB      (OFF_SLABEL + 32768)       // float4[8192] sorted boxes
#define OFF_OBOX    (OFF_SB + 131072)          // float4[8192] sorted offset boxes
#define OFF_MASK    (OFF_OBOX + 131072)        // u64 mask_T[128][8192]  (TRANSPOSED: word-major)
// total ≈ 9.4 MiB

__device__ __forceinline__ unsigned order_key(float f) {
    unsigned u = __float_as_uint(f);
    return (u & 0x80000000u) ? ~u : (u | 0x80000000u);  // ascending uint == ascending float
}

__device__ __forceinline__ float get_width(const int* widthp) {
    int wi = widthp[0];
    return (wi > 0 && wi < 1000000) ? (float)wi : __int_as_float(wi);
}

// Recompute the combined (flip-adjusted) candidate `idx` straight from inputs.
__device__ __forceinline__ void fetch_cand(int idx, const float* b1, const float* b2,
                                           const float* s1, const float* s2,
                                           const int* l1, const int* l2, float wf,
                                           float& x1, float& y1, float& x2, float& y2,
                                           float& sc, int& lb) {
#pragma clang fp contract(off)
    if (idx < NCAND) {
        x1 = b1[idx*4+0]; y1 = b1[idx*4+1]; x2 = b1[idx*4+2]; y2 = b1[idx*4+3];
        sc = s1[idx]; lb = l1[idx];
    } else {
        int m = idx - NCAND;
        float bx1 = b2[m*4+0], by1 = b2[m*4+1], bx2 = b2[m*4+2], by2 = b2[m*4+3];
        x1 = wf - bx2; y1 = by1; x2 = wf - bx1; y2 = by2;   // undo hflip, same IEEE ops as ref
        sc = s2[m]; lb = l2[m];
    }
}

// ---------------- kernel 1: keys + global max coordinate ----------------
extern "C" __global__ __launch_bounds__(512)
void k_build(const float* __restrict__ b1, const float* __restrict__ b2,
             const float* __restrict__ s1, const float* __restrict__ s2,
             const int* __restrict__ l1, const int* __restrict__ l2,
             const int* __restrict__ widthp, char* __restrict__ ws)
{
#pragma clang fp contract(off)
    const int e = blockIdx.x * 512 + threadIdx.x;
    const float wf = get_width(widthp);
    float x1, y1, x2, y2, sc; int lb;
    fetch_cand(e, b1, b2, s1, s2, l1, l2, wf, x1, y1, x2, y2, sc, lb);

    float lmax = fmaxf(fmaxf(x1, y1), fmaxf(x2, y2));   // coords >= 0 (clipped)
    for (int d = 32; d > 0; d >>= 1) lmax = fmaxf(lmax, __shfl_xor(lmax, d));
    if ((threadIdx.x & 63) == 0)
        atomicMax(((int*)(ws + OFF_HDR)) + 1, __float_as_int(lmax));  // poison < 0, safe

    bool valid = sc >= SCORE_T;
    float s = valid ? sc : -1.0f;
    u64 key = ((u64)order_key(-s) << 32) | (unsigned)e;  // low bits = idx -> stable argsort
    ((u64*)(ws + OFF_KEYS))[e] = key;
}

// ---------------- kernel 2: counting sort, partial ranks ----------------
extern "C" __global__ __launch_bounds__(256)
void k_count(char* __restrict__ ws)
{
    __shared__ u64 tile[M2 / JSPLIT];
    const u64* keys = (const u64*)(ws + OFF_KEYS);
    const int i = blockIdx.x * 256 + threadIdx.x;
    const u64 mykey = keys[i];
    const int j0 = blockIdx.y * (M2 / JSPLIT);
    for (int q = threadIdx.x; q < M2 / JSPLIT; q += 256) tile[q] = keys[j0 + q];
    __syncthreads();
    int cnt = 0;
#pragma unroll 8
    for (int q = 0; q < M2 / JSPLIT; ++q) cnt += (tile[q] < mykey) ? 1 : 0;
    ((int*)(ws + OFF_PART))[blockIdx.y * M2 + i] = cnt;
}

// ---------------- kernel 3: combine ranks + scatter + V ----------------
extern "C" __global__ __launch_bounds__(1024)
void k_scatter(const float* __restrict__ b1, const float* __restrict__ b2,
               const float* __restrict__ s1, const float* __restrict__ s2,
               const int* __restrict__ l1, const int* __restrict__ l2,
               const int* __restrict__ widthp, char* __restrict__ ws)
{
#pragma clang fp contract(off)
    const int i = blockIdx.x * 1024 + threadIdx.x;
    const int* part = (const int*)(ws + OFF_PART);
    int rank = 0;
#pragma unroll
    for (int sp = 0; sp < JSPLIT; ++sp) rank += part[sp * M2 + i];

    const float wf = get_width(widthp);
    const float maxc = __int_as_float(((const int*)(ws + OFF_HDR))[1]) + 1.0f; // jnp.max(boxes)+1.0
    float x1, y1, x2, y2, sc; int lb;
    fetch_cand(i, b1, b2, s1, s2, l1, l2, wf, x1, y1, x2, y2, sc, lb);

    float off = (float)lb * maxc;               // one product then 4 adds, like ref
    float ox1 = x1 + off, oy1 = y1 + off, ox2 = x2 + off, oy2 = y2 + off;
    float area = (ox2 - ox1) * (oy2 - oy1);     // area of OFFSET boxes, like ref

    ((float4*)(ws + OFF_SB))[rank]   = make_float4(x1, y1, x2, y2);
    ((float4*)(ws + OFF_OBOX))[rank] = make_float4(ox1, oy1, ox2, oy2);
    ((float*)(ws + OFF_OAREA))[rank]  = area;
    ((float*)(ws + OFF_SSCORE))[rank] = sc;
    ((int*)(ws + OFF_SLABEL))[rank]   = lb;

    // valid entries (score>=T) sort strictly before invalid (-1): V = max valid rank + 1
    bool valid = sc >= SCORE_T;
    u64 bal = __ballot(valid);
    int vmax = valid ? rank + 1 : INT32_MIN;
    for (int d = 32; d > 0; d >>= 1) vmax = max(vmax, __shfl_xor(vmax, d));
    if ((threadIdx.x & 63) == 0 && bal)
        atomicMax((int*)(ws + OFF_HDR), vmax);  // poison < 0, safe
}

// ---------------- kernel 4: lower-triangle conflict bitmask (TRANSPOSED store) ----------------
// grid (128, 32), 4 waves/block; wave g handles col word y = by*4+g vs row chunk x.
// Row boxes staged once per block in LDS (4x reuse, same-address broadcast reads).
extern "C" __global__ __launch_bounds__(256)
void k_mask(char* __restrict__ ws)
{
#pragma clang fp contract(off)
    __shared__ float4 sbox[64];
    __shared__ float  sarea[64];
    const int x = blockIdx.x;                   // row chunk
    const int V = ((const int*)(ws + OFF_HDR))[0];
    if (x * 64 >= V) return;                    // rows >= V never scanned

    const float4* obox  = (const float4*)(ws + OFF_OBOX);
    const float*  oarea = (const float*) (ws + OFF_OAREA);
    u64* maskT = (u64*)(ws + OFF_MASK);

    const int tid = threadIdx.x;
    if (tid < 64) { sbox[tid] = obox[x*64 + tid]; sarea[tid] = oarea[x*64 + tid]; }
    __syncthreads();

    const int g = tid >> 6, lane = tid & 63;
    const int y = blockIdx.y * 4 + g;           // col word
    if (y > x) return;                          // strictly-upper words never read (after barrier)

    const int col  = y * 64 + lane;
    const float4 cb = obox[col];
    const float  ca = oarea[col];

    for (int r = 0; r < 64; ++r) {
        int row = x * 64 + r;
        float4 rb = sbox[r];                    // LDS broadcast
        float  ra = sarea[r];
        float ltx = fmaxf(rb.x, cb.x);
        float lty = fmaxf(rb.y, cb.y);
        float rbx = fminf(rb.z, cb.z);
        float rby = fminf(rb.w, cb.w);
        float wx = fmaxf(rbx - ltx, 0.0f);      // jnp.clip(rb-lt, 0)
        float wy = fmaxf(rby - lty, 0.0f);
        float inter = wx * wy;
        float denom = ((ra + ca) - inter) + 1e-9f;  // ref association order
        float iou = inter / denom;
        u64 m = __ballot((col < row) && (iou > IOU_T));
        if (lane == 0) maskT[(size_t)y * M2 + row] = m;
    }
}

// ---------------- kernel 5: single-block LDS-chained exact NMS + fused output ----------------
// 16 waves; wave g owns words g, g+16, ... Chain hops via LDS publish/poll.
// Mask rows prefetched 8-deep in ping-pong register chunks. The asm memory barrier
// after each ISSUE pins the loads there (R6 lesson: without it the compiler sinks
// loads into the consume -> VGPR_Count 44 and zero prefetch). s_sleep(1) in the
// spin keeps waiting waves off the publisher's issue slots.
#define ISSUE_CHUNK(BUF, BASE)                                                  \
    _Pragma("unroll")                                                           \
    for (int i_ = 0; i_ < 8; ++i_) {                                            \
        int w_ = (BASE) + i_;                                                   \
        if (w_ < W) BUF[i_] = maskT[(size_t)w_ * M2 + R];                       \
    }                                                                           \
    asm volatile("" ::: "memory");   /* pin load issue here */

#define CONSUME_CHUNK(BUF, BASE)                                                \
    _Pragma("unroll")                                                           \
    for (int i_ = 0; i_ < 8; ++i_) {                                            \
        int w_ = (BASE) + i_;                                                   \
        if (w_ < W) {                                                           \
            int guard_ = 0;                                                     \
            while (__hip_atomic_load(&s_prog, __ATOMIC_ACQUIRE,                 \
                   __HIP_MEMORY_SCOPE_WORKGROUP) <= w_ &&                       \
                   ++guard_ < (1 << 20)) {                                      \
                __builtin_amdgcn_s_sleep(1);                                    \
            }                                                                   \
            acc |= BUF[i_] & __hip_atomic_load(&keep_lds[w_], __ATOMIC_RELAXED, \
                   __HIP_MEMORY_SCOPE_WORKGROUP);                               \
        }                                                                       \
    }

extern "C" __global__ __launch_bounds__(1024)
void k_nms_out(char* __restrict__ ws, float* __restrict__ out)
{
    __shared__ u64 keep_lds[NWORDS];
    __shared__ int s_prog;
    const int tid = threadIdx.x;
    const int g = tid >> 6, lane = tid & 63;
    const int V = ((const int*)(ws + OFF_HDR))[0];
    const int nw = (V > 0) ? ((V + 63) >> 6) : 0;   // chain is the word prefix [0, nw)
    const u64* maskT = (const u64*)(ws + OFF_MASK);

    if (tid < NWORDS) keep_lds[tid] = 0;        // defined fallback if guard ever expires
    if (tid == 0) s_prog = 0;
    __syncthreads();

    for (int W = g; W < NWORDS; W += 16) {
        if (W >= nw) {                          // fully-invalid word: keep = 0 (already), no chain
            continue;
        }
        const int R = W * 64 + lane;
        const u64 diag = maskT[(size_t)W * M2 + R];  // in-word lower-triangle conflicts
        u64 acc = 0;
        u64 A[8], B[8];
        ISSUE_CHUNK(A, 0)
        ISSUE_CHUNK(B, 8)
        CONSUME_CHUNK(A, 0)
        ISSUE_CHUNK(A, 16)
        CONSUME_CHUNK(B, 8)
        ISSUE_CHUNK(B, 24)
        CONSUME_CHUNK(A, 16)
        ISSUE_CHUNK(A, 32)
        CONSUME_CHUNK(B, 24)
        ISSUE_CHUNK(B, 40)
        CONSUME_CHUNK(A, 32)
        ISSUE_CHUNK(A, 48)
        CONSUME_CHUNK(B, 40)
        ISSUE_CHUNK(B, 56)
        CONSUME_CHUNK(A, 48)
        ISSUE_CHUNK(A, 64)
        CONSUME_CHUNK(B, 56)
        ISSUE_CHUNK(B, 72)
        CONSUME_CHUNK(A, 64)
        ISSUE_CHUNK(A, 80)
        CONSUME_CHUNK(B, 72)
        ISSUE_CHUNK(B, 88)
        CONSUME_CHUNK(A, 80)
        ISSUE_CHUNK(A, 96)
        CONSUME_CHUNK(B, 88)
        ISSUE_CHUNK(B, 104)
        CONSUME_CHUNK(A, 96)
        ISSUE_CHUNK(A, 112)
        CONSUME_CHUNK(B, 104)
        ISSUE_CHUNK(B, 120)
        CONSUME_CHUNK(A, 112)
        CONSUME_CHUNK(B, 120)

        const bool live = (R < V) && (acc == 0);     // not suppressed by earlier kept words
        u64 k = __ballot(live);
        for (int it = 0; it < 64; ++it) {            // unique triangular fixed point == greedy
            bool killed = (diag & k) != 0;
            u64 k2 = __ballot(live && !killed);
            if (k2 == k) break;
            k = k2;
        }
        if (lane == 0) {
            __hip_atomic_store(&keep_lds[W], k, __ATOMIC_RELAXED, __HIP_MEMORY_SCOPE_WORKGROUP);
            __hip_atomic_store(&s_prog, W + 1, __ATOMIC_RELEASE, __HIP_MEMORY_SCOPE_WORKGROUP);
        }
    }
    __syncthreads();

    // fused masked outputs: d_out (f32) = boxes[8192*4] | labels[8192] | scores[8192] | keeps[8192]
    for (int i = 0; i < M2 / 1024; ++i) {
        int p = tid + i * 1024;
        int kb = (int)((keep_lds[p >> 6] >> (p & 63)) & 1ull);
        float4 bx = ((const float4*)(ws + OFF_SB))[p];
        if (!kb) bx = make_float4(0.f, 0.f, 0.f, 0.f);
        ((float4*)out)[p] = bx;
        out[M2*4 + p] = kb ? (float)((const int*)(ws + OFF_SLABEL))[p] : -1.0f;
        out[M2*5 + p] = kb ? ((const float*)(ws + OFF_SSCORE))[p] : 0.0f;
        out[M2*6 + p] = kb ? 1.0f : 0.0f;
    }
}

extern "C" void kernel_launch(void* const* d_in, const int* in_sizes, int n_in,
                              void* d_out, int out_size, void* d_ws, size_t ws_size,
                              hipStream_t stream)
{
    const float* boxes1  = (const float*)d_in[0];
    const float* boxes2  = (const float*)d_in[1];
    const float* scores1 = (const float*)d_in[2];
    const float* scores2 = (const float*)d_in[3];
    const int*   labels1 = (const int*)d_in[4];
    const int*   labels2 = (const int*)d_in[5];
    const int*   widthp  = (const int*)d_in[6];
    char* ws = (char*)d_ws;

    hipLaunchKernelGGL(k_build, dim3(M2 / 512), dim3(512), 0, stream,
                       boxes1, boxes2, scores1, scores2, labels1, labels2, widthp, ws);
    hipLaunchKernelGGL(k_count, dim3(M2 / 256, JSPLIT), dim3(256), 0, stream, ws);
    hipLaunchKernelGGL(k_scatter, dim3(M2 / 1024), dim3(1024), 0, stream,
                       boxes1, boxes2, scores1, scores2, labels1, labels2, widthp, ws);
    hipLaunchKernelGGL(k_mask, dim3(NWORDS, 32), dim3(256), 0, stream, ws);
    hipLaunchKernelGGL(k_nms_out, dim3(1), dim3(1024), 0, stream, ws, (float*)d_out);
}

// Round 8
// 116.518 us; speedup vs baseline: 2.5711x; 2.5441x over previous
//
#include <hip/hip_runtime.h>
#include <stdint.h>

typedef unsigned long long u64;

#define NCAND   4096
#define M2      8192            // 2N
#define NCLS    91
#define SCORE_T 0.5f
#define IOU_T   0.5f
#define JSPLIT  16              // j-range splits for the counting sort
#define MAXMEMB 512             // per-class member capacity (mean ~45, 512 is >>10 sigma)

// ---------------- workspace layout (bytes) ----------------
// hdr[0] = V (atomicMax in k_scatter; 0xAA poison is negative -> no init needed)
// hdr[1] = maxcoord f32 bits (atomicMax in k_build; poison negative -> safe)
#define OFF_HDR     0
#define OFF_KEYS    4096                       // u64[8192]
#define OFF_PART    (OFF_KEYS + 65536)         // int[JSPLIT][8192]
#define OFF_OAREA   (OFF_PART + JSPLIT*32768)  // float[8192]
#define OFF_SSCORE  (OFF_OAREA + 32768)        // float[8192] sorted original scores
#define OFF_SLABEL  (OFF_SSCORE + 32768)       // int[8192]   sorted labels
#define OFF_SB      (OFF_SLABEL + 32768)       // float4[8192] sorted boxes
#define OFF_OBOX    (OFF_SB + 131072)          // float4[8192] sorted offset boxes
// total ≈ 1.4 MiB

__device__ __forceinline__ unsigned order_key(float f) {
    unsigned u = __float_as_uint(f);
    return (u & 0x80000000u) ? ~u : (u | 0x80000000u);  // ascending uint == ascending float
}

__device__ __forceinline__ float get_width(const int* widthp) {
    int wi = widthp[0];
    return (wi > 0 && wi < 1000000) ? (float)wi : __int_as_float(wi);
}

// Reference-exact IoU on offset boxes. fmaxf/fminf symmetric; (aa+ba) commutative IEEE,
// so suppressor/suppressee argument order matches the ref's area[i]+area[j] either way.
__device__ __forceinline__ float iou5(float4 a, float aa, float4 b, float ba) {
#pragma clang fp contract(off)
    float ltx = fmaxf(a.x, b.x);
    float lty = fmaxf(a.y, b.y);
    float rbx = fminf(a.z, b.z);
    float rby = fminf(a.w, b.w);
    float wx = fmaxf(rbx - ltx, 0.0f);          // jnp.clip(rb-lt, 0)
    float wy = fmaxf(rby - lty, 0.0f);
    float inter = wx * wy;
    return inter / (((aa + ba) - inter) + 1e-9f);
}

// Recompute the combined (flip-adjusted) candidate `idx` straight from inputs.
__device__ __forceinline__ void fetch_cand(int idx, const float* b1, const float* b2,
                                           const float* s1, const float* s2,
                                           const int* l1, const int* l2, float wf,
                                           float& x1, float& y1, float& x2, float& y2,
                                           float& sc, int& lb) {
#pragma clang fp contract(off)
    if (idx < NCAND) {
        x1 = b1[idx*4+0]; y1 = b1[idx*4+1]; x2 = b1[idx*4+2]; y2 = b1[idx*4+3];
        sc = s1[idx]; lb = l1[idx];
    } else {
        int m = idx - NCAND;
        float bx1 = b2[m*4+0], by1 = b2[m*4+1], bx2 = b2[m*4+2], by2 = b2[m*4+3];
        x1 = wf - bx2; y1 = by1; x2 = wf - bx1; y2 = by2;   // undo hflip, same IEEE ops as ref
        sc = s2[m]; lb = l2[m];
    }
}

// ---------------- kernel 1: keys + global max coordinate ----------------
extern "C" __global__ __launch_bounds__(512)
void k_build(const float* __restrict__ b1, const float* __restrict__ b2,
             const float* __restrict__ s1, const float* __restrict__ s2,
             const int* __restrict__ l1, const int* __restrict__ l2,
             const int* __restrict__ widthp, char* __restrict__ ws)
{
#pragma clang fp contract(off)
    const int e = blockIdx.x * 512 + threadIdx.x;
    const float wf = get_width(widthp);
    float x1, y1, x2, y2, sc; int lb;
    fetch_cand(e, b1, b2, s1, s2, l1, l2, wf, x1, y1, x2, y2, sc, lb);

    float lmax = fmaxf(fmaxf(x1, y1), fmaxf(x2, y2));   // coords >= 0 (clipped)
    for (int d = 32; d > 0; d >>= 1) lmax = fmaxf(lmax, __shfl_xor(lmax, d));
    if ((threadIdx.x & 63) == 0)
        atomicMax(((int*)(ws + OFF_HDR)) + 1, __float_as_int(lmax));  // poison < 0, safe

    bool valid = sc >= SCORE_T;
    float s = valid ? sc : -1.0f;
    u64 key = ((u64)order_key(-s) << 32) | (unsigned)e;  // low bits = idx -> stable argsort
    ((u64*)(ws + OFF_KEYS))[e] = key;
}

// ---------------- kernel 2: counting sort, partial ranks ----------------
extern "C" __global__ __launch_bounds__(256)
void k_count(char* __restrict__ ws)
{
    __shared__ u64 tile[M2 / JSPLIT];
    const u64* keys = (const u64*)(ws + OFF_KEYS);
    const int i = blockIdx.x * 256 + threadIdx.x;
    const u64 mykey = keys[i];
    const int j0 = blockIdx.y * (M2 / JSPLIT);
    for (int q = threadIdx.x; q < M2 / JSPLIT; q += 256) tile[q] = keys[j0 + q];
    __syncthreads();
    int cnt = 0;
#pragma unroll 8
    for (int q = 0; q < M2 / JSPLIT; ++q) cnt += (tile[q] < mykey) ? 1 : 0;
    ((int*)(ws + OFF_PART))[blockIdx.y * M2 + i] = cnt;
}

// ---------------- kernel 3: combine ranks + scatter + V ----------------
extern "C" __global__ __launch_bounds__(1024)
void k_scatter(const float* __restrict__ b1, const float* __restrict__ b2,
               const float* __restrict__ s1, const float* __restrict__ s2,
               const int* __restrict__ l1, const int* __restrict__ l2,
               const int* __restrict__ widthp, char* __restrict__ ws)
{
#pragma clang fp contract(off)
    const int i = blockIdx.x * 1024 + threadIdx.x;
    const int* part = (const int*)(ws + OFF_PART);
    int rank = 0;
#pragma unroll
    for (int sp = 0; sp < JSPLIT; ++sp) rank += part[sp * M2 + i];

    const float wf = get_width(widthp);
    const float maxc = __int_as_float(((const int*)(ws + OFF_HDR))[1]) + 1.0f; // jnp.max(boxes)+1.0
    float x1, y1, x2, y2, sc; int lb;
    fetch_cand(i, b1, b2, s1, s2, l1, l2, wf, x1, y1, x2, y2, sc, lb);

    float off = (float)lb * maxc;               // one product then 4 adds, like ref
    float ox1 = x1 + off, oy1 = y1 + off, ox2 = x2 + off, oy2 = y2 + off;
    float area = (ox2 - ox1) * (oy2 - oy1);     // area of OFFSET boxes, like ref

    ((float4*)(ws + OFF_SB))[rank]   = make_float4(x1, y1, x2, y2);
    ((float4*)(ws + OFF_OBOX))[rank] = make_float4(ox1, oy1, ox2, oy2);
    ((float*)(ws + OFF_OAREA))[rank]  = area;
    ((float*)(ws + OFF_SSCORE))[rank] = sc;
    ((int*)(ws + OFF_SLABEL))[rank]   = lb;

    // valid entries (score>=T) sort strictly before invalid (-1): V = max valid rank + 1
    bool valid = sc >= SCORE_T;
    u64 bal = __ballot(valid);
    int vmax = valid ? rank + 1 : INT32_MIN;
    for (int d = 32; d > 0; d >>= 1) vmax = max(vmax, __shfl_xor(vmax, d));
    if ((threadIdx.x & 63) == 0 && bal)
        atomicMax((int*)(ws + OFF_HDR), vmax);  // poison < 0, safe
}

// ---------------- kernel 4: per-class greedy NMS + fused outputs ----------------
// batched_nms == independent NMS per class (cross-class IoU is exactly 0 in the ref's
// own arithmetic: class offsets differ by >= maxc so rb-lt <= -1 clips to 0).
// One wave per class (91 waves of 96); each wave: ballot-compact its members from the
// sorted arrays (ascending rank == descending score), then chunk-of-64 greedy:
// in-chunk 64x64 lower-tri conflict word + ballot fixpoint (== greedy, validated),
// cross-chunk suppression from already-kept members. Writes its rows of d_out directly.
// d_out (f32): boxes[8192*4] | labels[8192] | scores[8192] | keeps[8192]
extern "C" __global__ __launch_bounds__(256)
void k_classnms(const char* __restrict__ ws, float* __restrict__ out)
{
#pragma clang fp contract(off)
    __shared__ unsigned short memb[4][MAXMEMB];
    __shared__ float4 cbox[4][64];
    __shared__ float  carea[4][64];
    __shared__ u64    kmask[4][MAXMEMB / 64];

    const int tid = threadIdx.x;
    const int g = tid >> 6, lane = tid & 63;
    const int wid = blockIdx.x * 4 + g;          // 0..95
    int V = ((const int*)(ws + OFF_HDR))[0];
    if (V < 0) V = 0; if (V > M2) V = M2;

    const int*    slabel = (const int*)   (ws + OFF_SLABEL);
    const float4* obox   = (const float4*)(ws + OFF_OBOX);
    const float*  oarea  = (const float*) (ws + OFF_OAREA);
    const float4* sb     = (const float4*)(ws + OFF_SB);
    const float*  sscore = (const float*) (ws + OFF_SSCORE);

    // invalid tail [V, M2): defaults, striped across all 96 waves
    for (int p = V + wid * 64 + lane; p < M2; p += 96 * 64) {
        ((float4*)out)[p] = make_float4(0.f, 0.f, 0.f, 0.f);
        out[M2*4 + p] = -1.0f;
        out[M2*5 + p] = 0.0f;
        out[M2*6 + p] = 0.0f;
    }
    if (wid >= NCLS) return;
    const int c = wid;                           // this wave's class

    // ---- collect members of class c in ascending rank (= descending score) ----
    int n = 0;
    for (int p0 = 0; p0 < V; p0 += 256) {        // 4x64 per iteration, batched loads
        int pA = p0 + lane, pB = p0 + 64 + lane, pC = p0 + 128 + lane, pD = p0 + 192 + lane;
        int lA = (pA < V) ? slabel[pA] : -1;
        int lB = (pB < V) ? slabel[pB] : -1;
        int lC = (pC < V) ? slabel[pC] : -1;
        int lD = (pD < V) ? slabel[pD] : -1;
        const u64 lt = (1ull << lane) - 1;
        u64 bal;
        bal = __ballot(lA == c);
        if (lA == c) { int q = n + __popcll(bal & lt); if (q < MAXMEMB) memb[g][q] = (unsigned short)pA; }
        n += __popcll(bal);
        bal = __ballot(lB == c);
        if (lB == c) { int q = n + __popcll(bal & lt); if (q < MAXMEMB) memb[g][q] = (unsigned short)pB; }
        n += __popcll(bal);
        bal = __ballot(lC == c);
        if (lC == c) { int q = n + __popcll(bal & lt); if (q < MAXMEMB) memb[g][q] = (unsigned short)pC; }
        n += __popcll(bal);
        bal = __ballot(lD == c);
        if (lD == c) { int q = n + __popcll(bal & lt); if (q < MAXMEMB) memb[g][q] = (unsigned short)pD; }
        n += __popcll(bal);
    }
    if (n > MAXMEMB) n = MAXMEMB;                // statistically unreachable

    // ---- greedy NMS over members, 64 at a time ----
    for (int t = 0; t * 64 < n; ++t) {
        int j = t * 64 + lane;
        bool have = j < n;
        int p = have ? (int)memb[g][j] : 0;
        float4 mb = make_float4(0.f, 0.f, 0.f, 0.f);
        float ma = 0.f;
        if (have) { mb = obox[p]; ma = oarea[p]; }
        cbox[g][lane] = mb;                      // wave-private stage for broadcast
        carea[g][lane] = ma;

        // suppression by kept members of earlier chunks (uniform bit-iteration)
        bool supp = false;
        for (int tt = 0; tt < t; ++tt) {
            u64 kb = kmask[g][tt];
            while (kb) {
                int jj = __ffsll(kb) - 1; kb &= kb - 1;
                int pp = (int)memb[g][tt * 64 + jj];
                float4 ob = obox[pp];            // wave-uniform address -> broadcast
                float  oa = oarea[pp];
                supp = supp || (iou5(mb, ma, ob, oa) > IOU_T);
            }
        }

        // in-chunk lower-triangle conflict word (bit jj: earlier member jj conflicts me)
        u64 diag = 0;
        int lim = n - t * 64; if (lim > 64) lim = 64;
        for (int jj = 0; jj < lim; ++jj) {
            float4 ob = cbox[g][jj];             // LDS same-address broadcast
            float  oa = carea[g][jj];
            if (have && jj < lane && (iou5(mb, ma, ob, oa) > IOU_T)) diag |= 1ull << jj;
        }

        bool live = have && !supp;
        u64 k = __ballot(live);
        for (int it = 0; it < 64; ++it) {        // unique triangular fixed point == greedy
            bool killed = (diag & k) != 0;
            u64 k2 = __ballot(live && !killed);
            if (k2 == k) break;
            k = k2;
        }
        if (lane == 0) kmask[g][t] = k;          // same-wave read next iteration (ordered)

        if (have) {
            bool kept = (k >> lane) & 1ull;
            float4 bx = kept ? sb[p] : make_float4(0.f, 0.f, 0.f, 0.f);
            ((float4*)out)[p] = bx;
            out[M2*4 + p] = kept ? (float)c : -1.0f;
            out[M2*5 + p] = kept ? sscore[p] : 0.0f;
            out[M2*6 + p] = kept ? 1.0f : 0.0f;
        }
    }
}

extern "C" void kernel_launch(void* const* d_in, const int* in_sizes, int n_in,
                              void* d_out, int out_size, void* d_ws, size_t ws_size,
                              hipStream_t stream)
{
    const float* boxes1  = (const float*)d_in[0];
    const float* boxes2  = (const float*)d_in[1];
    const float* scores1 = (const float*)d_in[2];
    const float* scores2 = (const float*)d_in[3];
    const int*   labels1 = (const int*)d_in[4];
    const int*   labels2 = (const int*)d_in[5];
    const int*   widthp  = (const int*)d_in[6];
    char* ws = (char*)d_ws;

    hipLaunchKernelGGL(k_build, dim3(M2 / 512), dim3(512), 0, stream,
                       boxes1, boxes2, scores1, scores2, labels1, labels2, widthp, ws);
    hipLaunchKernelGGL(k_count, dim3(M2 / 256, JSPLIT), dim3(256), 0, stream, ws);
    hipLaunchKernelGGL(k_scatter, dim3(M2 / 1024), dim3(1024), 0, stream,
                       boxes1, boxes2, scores1, scores2, labels1, labels2, widthp, ws);
    hipLaunchKernelGGL(k_classnms, dim3(24), dim3(256), 0, stream, ws, (float*)d_out);
}

// Round 10
// 113.601 us; speedup vs baseline: 2.6371x; 1.0257x over previous
//
#include <hip/hip_runtime.h>
#include <stdint.h>

typedef unsigned long long u64;

#define NCAND   4096
#define M2      8192            // 2N
#define NCLS    91
#define SCORE_T 0.5f
#define IOU_T   0.5f
#define JSPLIT  16              // j-range splits for the counting sort
#define MAXMEMB 512             // per-class member capacity (mean ~45, 512 is >>10 sigma)

// ---------------- workspace layout (bytes) ----------------
// hdr[0] = V (atomicMax in k_scatter; 0xAA poison is negative -> no init needed)
// hdr[1] = maxcoord f32 bits (atomicMax in k_count2; poison negative -> safe)
#define OFF_HDR     0
#define OFF_PART    4096                       // int[JSPLIT][8192]
#define OFF_OAREA   (OFF_PART + JSPLIT*32768)  // float[8192]
#define OFF_SSCORE  (OFF_OAREA + 32768)        // float[8192] sorted original scores
#define OFF_SLABEL  (OFF_SSCORE + 32768)       // int[8192]   sorted labels
#define OFF_SB      (OFF_SLABEL + 32768)       // float4[8192] sorted boxes
#define OFF_OBOX    (OFF_SB + 131072)          // float4[8192] sorted offset boxes
// total ≈ 1.3 MiB

__device__ __forceinline__ unsigned order_key(float f) {
    unsigned u = __float_as_uint(f);
    return (u & 0x80000000u) ? ~u : (u | 0x80000000u);  // ascending uint == ascending float
}

__device__ __forceinline__ float get_width(const int* widthp) {
    int wi = widthp[0];
    return (wi > 0 && wi < 1000000) ? (float)wi : __int_as_float(wi);
}

// Reference-exact IoU on offset boxes. fmaxf/fminf symmetric; (aa+ba) commutative IEEE,
// so suppressor/suppressee argument order matches the ref's area[i]+area[j] either way.
__device__ __forceinline__ float iou5(float4 a, float aa, float4 b, float ba) {
#pragma clang fp contract(off)
    float ltx = fmaxf(a.x, b.x);
    float lty = fmaxf(a.y, b.y);
    float rbx = fminf(a.z, b.z);
    float rby = fminf(a.w, b.w);
    float wx = fmaxf(rbx - ltx, 0.0f);          // jnp.clip(rb-lt, 0)
    float wy = fmaxf(rby - lty, 0.0f);
    float inter = wx * wy;
    return inter / (((aa + ba) - inter) + 1e-9f);
}

// Recompute the combined (flip-adjusted) candidate `idx` straight from inputs.
__device__ __forceinline__ void fetch_cand(int idx, const float* b1, const float* b2,
                                           const float* s1, const float* s2,
                                           const int* l1, const int* l2, float wf,
                                           float& x1, float& y1, float& x2, float& y2,
                                           float& sc, int& lb) {
#pragma clang fp contract(off)
    if (idx < NCAND) {
        x1 = b1[idx*4+0]; y1 = b1[idx*4+1]; x2 = b1[idx*4+2]; y2 = b1[idx*4+3];
        sc = s1[idx]; lb = l1[idx];
    } else {
        int m = idx - NCAND;
        float bx1 = b2[m*4+0], by1 = b2[m*4+1], bx2 = b2[m*4+2], by2 = b2[m*4+3];
        x1 = wf - bx2; y1 = by1; x2 = wf - bx1; y2 = by2;   // undo hflip, same IEEE ops as ref
        sc = s2[m]; lb = l2[m];
    }
}

__device__ __forceinline__ u64 make_key(float sc, int e) {
    bool valid = sc >= SCORE_T;
    float s = valid ? sc : -1.0f;
    return ((u64)order_key(-s) << 32) | (unsigned)e;     // low bits = idx -> stable argsort
}

// ---------------- kernel 1: fused keys + max-coord + counting-sort partial ranks ----------
// grid (32, JSPLIT) x 256. Block (bx,by): i = bx*256+tid, j-tile = [by*512, by*512+512).
// Keys are recomputed from raw inputs (no key array round-trip). by==0 blocks also do
// the global max-coord reduction. Invalid i skip the compare loop (rank never consumed).
extern "C" __global__ __launch_bounds__(256)
void k_count2(const float* __restrict__ b1, const float* __restrict__ b2,
              const float* __restrict__ s1, const float* __restrict__ s2,
              const int* __restrict__ l1, const int* __restrict__ l2,
              const int* __restrict__ widthp, char* __restrict__ ws)
{
#pragma clang fp contract(off)
    __shared__ u64 tile[M2 / JSPLIT];
    const int tid = threadIdx.x;
    const int i = blockIdx.x * 256 + tid;
    const float wf = get_width(widthp);

    // own candidate -> key + validity (+ max-coord contribution once, via by==0 blocks)
    float x1, y1, x2, y2, sc; int lb;
    fetch_cand(i, b1, b2, s1, s2, l1, l2, wf, x1, y1, x2, y2, sc, lb);
    const u64 mykey = make_key(sc, i);
    const bool valid = sc >= SCORE_T;
    if (blockIdx.y == 0) {
        float lmax = fmaxf(fmaxf(x1, y1), fmaxf(x2, y2));   // coords >= 0 (clipped)
        for (int d = 32; d > 0; d >>= 1) lmax = fmaxf(lmax, __shfl_xor(lmax, d));
        if ((tid & 63) == 0)
            atomicMax(((int*)(ws + OFF_HDR)) + 1, __float_as_int(lmax));  // poison < 0, safe
    }

    // j-tile keys (2 per thread), recomputed from inputs
    const int j0 = blockIdx.y * (M2 / JSPLIT);
    for (int q = tid; q < M2 / JSPLIT; q += 256) {
        float tx1, ty1, tx2, ty2, tsc; int tlb;
        fetch_cand(j0 + q, b1, b2, s1, s2, l1, l2, wf, tx1, ty1, tx2, ty2, tsc, tlb);
        tile[q] = make_key(tsc, j0 + q);
    }
    __syncthreads();

    if (valid) {
        int cnt = 0;
#pragma unroll 8
        for (int q = 0; q < M2 / JSPLIT; ++q) cnt += (tile[q] < mykey) ? 1 : 0;
        ((int*)(ws + OFF_PART))[blockIdx.y * M2 + i] = cnt;
    }
}

// ---------------- kernel 2: combine ranks + scatter (valid only) + V ----------------
extern "C" __global__ __launch_bounds__(1024)
void k_scatter(const float* __restrict__ b1, const float* __restrict__ b2,
               const float* __restrict__ s1, const float* __restrict__ s2,
               const int* __restrict__ l1, const int* __restrict__ l2,
               const int* __restrict__ widthp, char* __restrict__ ws)
{
#pragma clang fp contract(off)
    const int i = blockIdx.x * 1024 + threadIdx.x;
    const float wf = get_width(widthp);
    float x1, y1, x2, y2, sc; int lb;
    fetch_cand(i, b1, b2, s1, s2, l1, l2, wf, x1, y1, x2, y2, sc, lb);
    const bool valid = sc >= SCORE_T;

    int rank = 0;
    if (valid) {
        const int* part = (const int*)(ws + OFF_PART);
#pragma unroll
        for (int sp = 0; sp < JSPLIT; ++sp) rank += part[sp * M2 + i];

        const float maxc = __int_as_float(((const int*)(ws + OFF_HDR))[1]) + 1.0f; // jnp.max+1
        float off = (float)lb * maxc;           // one product then 4 adds, like ref
        float ox1 = x1 + off, oy1 = y1 + off, ox2 = x2 + off, oy2 = y2 + off;
        float area = (ox2 - ox1) * (oy2 - oy1); // area of OFFSET boxes, like ref

        ((float4*)(ws + OFF_SB))[rank]   = make_float4(x1, y1, x2, y2);
        ((float4*)(ws + OFF_OBOX))[rank] = make_float4(ox1, oy1, ox2, oy2);
        ((float*)(ws + OFF_OAREA))[rank]  = area;
        ((float*)(ws + OFF_SSCORE))[rank] = sc;
        ((int*)(ws + OFF_SLABEL))[rank]   = lb;
    }

    // valid entries sort strictly before invalid: V = max valid rank + 1
    u64 bal = __ballot(valid);
    int vmax = valid ? rank + 1 : INT32_MIN;
    for (int d = 32; d > 0; d >>= 1) vmax = max(vmax, __shfl_xor(vmax, d));
    if ((threadIdx.x & 63) == 0 && bal)
        atomicMax((int*)(ws + OFF_HDR), vmax);  // poison < 0, safe
}

// ---------------- kernel 3: per-class greedy NMS + fused outputs ----------------
// batched_nms == independent NMS per class (cross-class IoU is exactly 0 in the ref's
// own arithmetic: class offsets differ by >= maxc so rb-lt <= -1 clips to 0).
// One wave per class (91 waves of 96); each wave: ballot-compact its members from the
// sorted arrays (ascending rank == descending score), then chunk-of-64 greedy:
// in-chunk 64x64 lower-tri conflict word + ballot fixpoint (== greedy, validated),
// cross-chunk suppression from already-kept members. Writes its rows of d_out directly.
// d_out (f32): boxes[8192*4] | labels[8192] | scores[8192] | keeps[8192]
extern "C" __global__ __launch_bounds__(256)
void k_classnms(const char* __restrict__ ws, float* __restrict__ out)
{
#pragma clang fp contract(off)
    __shared__ unsigned short memb[4][MAXMEMB];
    __shared__ float4 cbox[4][64];
    __shared__ float  carea[4][64];
    __shared__ u64    kmask[4][MAXMEMB / 64];

    const int tid = threadIdx.x;
    const int g = tid >> 6, lane = tid & 63;
    const int wid = blockIdx.x * 4 + g;          // 0..95
    int V = ((const int*)(ws + OFF_HDR))[0];
    if (V < 0) V = 0; if (V > M2) V = M2;

    const int*    slabel = (const int*)   (ws + OFF_SLABEL);
    const float4* obox   = (const float4*)(ws + OFF_OBOX);
    const float*  oarea  = (const float*) (ws + OFF_OAREA);
    const float4* sb     = (const float4*)(ws + OFF_SB);
    const float*  sscore = (const float*) (ws + OFF_SSCORE);

    // invalid tail [V, M2): defaults, striped across all 96 waves
    for (int p = V + wid * 64 + lane; p < M2; p += 96 * 64) {
        ((float4*)out)[p] = make_float4(0.f, 0.f, 0.f, 0.f);
        out[M2*4 + p] = -1.0f;
        out[M2*5 + p] = 0.0f;
        out[M2*6 + p] = 0.0f;
    }
    if (wid >= NCLS) return;
    const int c = wid;                           // this wave's class

    // ---- collect members of class c in ascending rank (= descending score) ----
    int n = 0;
    for (int p0 = 0; p0 < V; p0 += 256) {        // 4x64 per iteration, batched loads
        int pA = p0 + lane, pB = p0 + 64 + lane, pC = p0 + 128 + lane, pD = p0 + 192 + lane;
        int lA = (pA < V) ? slabel[pA] : -1;
        int lB = (pB < V) ? slabel[pB] : -1;
        int lC = (pC < V) ? slabel[pC] : -1;
        int lD = (pD < V) ? slabel[pD] : -1;
        const u64 lt = (1ull << lane) - 1;
        u64 bal;
        bal = __ballot(lA == c);
        if (lA == c) { int q = n + __popcll(bal & lt); if (q < MAXMEMB) memb[g][q] = (unsigned short)pA; }
        n += __popcll(bal);
        bal = __ballot(lB == c);
        if (lB == c) { int q = n + __popcll(bal & lt); if (q < MAXMEMB) memb[g][q] = (unsigned short)pB; }
        n += __popcll(bal);
        bal = __ballot(lC == c);
        if (lC == c) { int q = n + __popcll(bal & lt); if (q < MAXMEMB) memb[g][q] = (unsigned short)pC; }
        n += __popcll(bal);
        bal = __ballot(lD == c);
        if (lD == c) { int q = n + __popcll(bal & lt); if (q < MAXMEMB) memb[g][q] = (unsigned short)pD; }
        n += __popcll(bal);
    }
    if (n > MAXMEMB) n = MAXMEMB;                // statistically unreachable

    // ---- greedy NMS over members, 64 at a time ----
    for (int t = 0; t * 64 < n; ++t) {
        int j = t * 64 + lane;
        bool have = j < n;
        int p = have ? (int)memb[g][j] : 0;
        float4 mb = make_float4(0.f, 0.f, 0.f, 0.f);
        float ma = 0.f;
        if (have) { mb = obox[p]; ma = oarea[p]; }
        cbox[g][lane] = mb;                      // wave-private stage for broadcast
        carea[g][lane] = ma;

        // suppression by kept members of earlier chunks (uniform bit-iteration)
        bool supp = false;
        for (int tt = 0; tt < t; ++tt) {
            u64 kb = kmask[g][tt];
            while (kb) {
                int jj = __ffsll(kb) - 1; kb &= kb - 1;
                int pp = (int)memb[g][tt * 64 + jj];
                float4 ob = obox[pp];            // wave-uniform address -> broadcast
                float  oa = oarea[pp];
                supp = supp || (iou5(mb, ma, ob, oa) > IOU_T);
            }
        }

        // in-chunk lower-triangle conflict word (bit jj: earlier member jj conflicts me)
        u64 diag = 0;
        int lim = n - t * 64; if (lim > 64) lim = 64;
        for (int jj = 0; jj < lim; ++jj) {
            float4 ob = cbox[g][jj];             // LDS same-address broadcast
            float  oa = carea[g][jj];
            if (have && jj < lane && (iou5(mb, ma, ob, oa) > IOU_T)) diag |= 1ull << jj;
        }

        bool live = have && !supp;
        u64 k = __ballot(live);
        for (int it = 0; it < 64; ++it) {        // unique triangular fixed point == greedy
            bool killed = (diag & k) != 0;
            u64 k2 = __ballot(live && !killed);
            if (k2 == k) break;
            k = k2;
        }
        if (lane == 0) kmask[g][t] = k;          // same-wave read next iteration (ordered)

        if (have) {
            bool kept = (k >> lane) & 1ull;
            float4 bx = kept ? sb[p] : make_float4(0.f, 0.f, 0.f, 0.f);
            ((float4*)out)[p] = bx;
            out[M2*4 + p] = kept ? (float)c : -1.0f;
            out[M2*5 + p] = kept ? sscore[p] : 0.0f;
            out[M2*6 + p] = kept ? 1.0f : 0.0f;
        }
    }
}

extern "C" void kernel_launch(void* const* d_in, const int* in_sizes, int n_in,
                              void* d_out, int out_size, void* d_ws, size_t ws_size,
                              hipStream_t stream)
{
    const float* boxes1  = (const float*)d_in[0];
    const float* boxes2  = (const float*)d_in[1];
    const float* scores1 = (const float*)d_in[2];
    const float* scores2 = (const float*)d_in[3];
    const int*   labels1 = (const int*)d_in[4];
    const int*   labels2 = (const int*)d_in[5];
    const int*   widthp  = (const int*)d_in[6];
    char* ws = (char*)d_ws;

    hipLaunchKernelGGL(k_count2, dim3(M2 / 256, JSPLIT), dim3(256), 0, stream,
                       boxes1, boxes2, scores1, scores2, labels1, labels2, widthp, ws);
    hipLaunchKernelGGL(k_scatter, dim3(M2 / 1024), dim3(1024), 0, stream,
                       boxes1, boxes2, scores1, scores2, labels1, labels2, widthp, ws);
    hipLaunchKernelGGL(k_classnms, dim3(24), dim3(256), 0, stream, ws, (float*)d_out);
}